// Round 12
// baseline (1938.523 us; speedup 1.0000x reference)
//
#include <hip/hip_runtime.h>
#include <hip/hip_bf16.h>
#include <cmath>

#define B_ 128
#define T_ 1024
#define D_ 128
#define U_ 256
#define EPS_ 0.01f
#define GAMMA_ 0.01f
#define NB 32            // batches per scan block (2 groups of 16)
#define NBLK (B_ / NB)   // 4 scan blocks

typedef __attribute__((ext_vector_type(8))) short bf16x8;
typedef __attribute__((ext_vector_type(4))) float f32x4;

// f32 -> bf16 round-to-nearest-even (bit math; one-time setup)
static __device__ __forceinline__ short f2bf(float f) {
  unsigned u = __builtin_bit_cast(unsigned, f);
  unsigned r = (u + 0x7FFFu + ((u >> 16) & 1u)) >> 16;
  return (short)r;
}
// per-step epilogue: native v_cvt (1 op, RTE)
static __device__ __forceinline__ short f2bf_fast(float f) {
  __hip_bfloat16 b(f);
  return __builtin_bit_cast(short, b);
}

// Swizzled byte offset into one bf16 state buffer s[16 rows][256 units].
// Row stride 512 B; XOR bits 4-7 with (row&15): all 16 rows distinct bank
// windows -> reads and writes <=2-way (free). Verified r9: conflicts = 0.
static __device__ __forceinline__ int sb_byte(int j, int u) {
  return j * 512 + ((u * 2) ^ ((j & 15) << 4));
}

// ================= Kernel 1: h = x @ V + bias (f32, unchanged) =============
#define HG_ROWS 32

__global__ __launch_bounds__(256) void h_gemm_kernel(
    const float* __restrict__ x, const float* __restrict__ V,
    const float* __restrict__ bias, float* __restrict__ out)
{
  const int tid = threadIdx.x;
  const size_t row0 = (size_t)blockIdx.x * HG_ROWS;

  __shared__ float xs[HG_ROWS][D_];
  __shared__ float vs[32][U_];

  {
    const float4* xg = reinterpret_cast<const float4*>(x + row0 * D_);
    float4* xs4 = reinterpret_cast<float4*>(&xs[0][0]);
    #pragma unroll
    for (int i = 0; i < 4; ++i) xs4[i * 256 + tid] = xg[i * 256 + tid];
  }

  float acc[HG_ROWS];
  {
    float b0 = bias[tid];
    #pragma unroll
    for (int r = 0; r < HG_ROWS; ++r) acc[r] = b0;
  }

  for (int c = 0; c < 4; ++c) {
    __syncthreads();
    {
      const float4* vg = reinterpret_cast<const float4*>(V + (size_t)(c * 32) * U_);
      float4* vs4 = reinterpret_cast<float4*>(&vs[0][0]);
      #pragma unroll
      for (int i = 0; i < 8; ++i) vs4[i * 256 + tid] = vg[i * 256 + tid];
    }
    __syncthreads();

    #pragma unroll 2
    for (int d4 = 0; d4 < 8; ++d4) {
      float v0 = vs[d4 * 4 + 0][tid];
      float v1 = vs[d4 * 4 + 1][tid];
      float v2 = vs[d4 * 4 + 2][tid];
      float v3 = vs[d4 * 4 + 3][tid];
      #pragma unroll
      for (int r = 0; r < HG_ROWS; ++r) {
        float4 xr = *reinterpret_cast<const float4*>(&xs[r][c * 32 + d4 * 4]);
        acc[r] = fmaf(xr.x, v0, acc[r]);
        acc[r] = fmaf(xr.y, v1, acc[r]);
        acc[r] = fmaf(xr.z, v2, acc[r]);
        acc[r] = fmaf(xr.w, v3, acc[r]);
      }
    }
  }

  float* og = out + row0 * U_;
  #pragma unroll
  for (int r = 0; r < HG_ROWS; ++r) og[(size_t)r * U_ + tid] = acc[r];
}

// ================= Kernel 2: MFMA scan, paired groups =======================
// 4 blocks x 512 threads (8 waves). Each block runs TWO independent 16-batch
// groups (A: b0..b0+15, B: b0+16..b0+31) sharing one barrier and the SAME
// bfrag (same M columns). Per interval: readA, readB, mfmaA, mfmaB, epiA,
// epiB, one raw barrier. B's independent chain fills the LDS/VALU pipe gaps
// left by A's latency (smoothing), and barrier cost per group-step halves.
// Groups share goff; B is addressed off a second uniform base (+16*T*U).
// Slot map (g,e) -> k = kt*32+8g+e on A and B sides (lane-uniform kt only —
// r10 lesson); C/D layout (m89-verified): col = l&15, row = 4*(l>>4) + reg.
__global__ __launch_bounds__(512, 2) void scan_mfma_kernel(
    const float* __restrict__ W, const float* __restrict__ x0,
    float* __restrict__ out)
{
  __shared__ __align__(16) char sA0[16 * 512];
  __shared__ __align__(16) char sA1[16 * 512];
  __shared__ __align__(16) char sB0[16 * 512];
  __shared__ __align__(16) char sB1[16 * 512];

  const int tid = threadIdx.x;
  const int w = tid >> 6;     // wave 0..7
  const int l = tid & 63;
  const int g = l >> 4;       // 0..3
  const int n16 = l & 15;
  const int b0 = blockIdx.x * NB;

  // ---- B fragments (static M columns), kt-indexed, shared by both groups
  bf16x8 bfrag[2][8];
  #pragma unroll
  for (int c = 0; c < 2; ++c) {
    const int u = 32 * w + 16 * c + n16;
    #pragma unroll
    for (int kt = 0; kt < 8; ++kt) {
      #pragma unroll
      for (int e = 0; e < 8; ++e) {
        const int k = kt * 32 + 8 * g + e;
        float mv = W[(size_t)k * U_ + u] - W[(size_t)u * U_ + k]
                   - ((k == u) ? GAMMA_ : 0.0f);
        bfrag[c][kt][e] = f2bf(mv);
      }
    }
  }

  // ---- f32 master state per group: lane owns rows 4g+i, cols u(c)
  float sfA[2][4], sfB[2][4];
  #pragma unroll
  for (int c = 0; c < 2; ++c) {
    float v = x0[32 * w + 16 * c + n16];
    #pragma unroll
    for (int i = 0; i < 4; ++i) { sfA[c][i] = v; sfB[c][i] = v; }
  }

  // ---- init bf16 state buffers (threads 0..255 handle unit u=tid)
  if (tid < U_) {
    short v = f2bf(x0[tid]);
    #pragma unroll
    for (int j = 0; j < 16; ++j) {
      *(short*)(&sA0[sb_byte(j, tid)]) = v;
      *(short*)(&sB0[sb_byte(j, tid)]) = v;
    }
  }

  // ---- shared u32 byte offsets (A-group batches); B uses base + 16*T*U
  unsigned goff[2][4];
  #pragma unroll
  for (int c = 0; c < 2; ++c) {
    const int u = 32 * w + 16 * c + n16;
    #pragma unroll
    for (int i = 0; i < 4; ++i)
      goff[c][i] = (unsigned)((b0 + 4 * g + i) * T_) * (U_ * 4u) + u * 4u;
  }

  __syncthreads();

  const char* outA = (const char*)out;
  const char* outB = (const char*)(out + (size_t)16 * T_ * U_);
  char* outAw = (char*)out;
  char* outBw = (char*)(out + (size_t)16 * T_ * U_);

  // ---- preload h: even/odd register sets per group
  float hAe[2][4], hAo[2][4], hBe[2][4], hBo[2][4];
  #pragma unroll
  for (int c = 0; c < 2; ++c)
    #pragma unroll
    for (int i = 0; i < 4; ++i) {
      hAe[c][i] = *(const float*)(outA + goff[c][i]);
      hAo[c][i] = *(const float*)(outA + goff[c][i] + 1024);
      hBe[c][i] = *(const float*)(outB + goff[c][i]);
      hBo[c][i] = *(const float*)(outB + goff[c][i] + 1024);
    }

  constexpr float LOG2E2 = 2.8853900817779268f;  // 2/ln2

  for (int it = 0; it < T_ / 2; ++it) {
    const bool pf = (it + 1 < T_ / 2);

    // ================= even step: read s?0, write s?1 =====================
    {
      // both groups' A-fragment reads issued up front (fills LDS pipe)
      bf16x8 afA[8], afB[8];
      #pragma unroll
      for (int kt = 0; kt < 8; ++kt)
        afA[kt] = *(const bf16x8*)(sA0 + n16 * 512
                                   + ((kt * 64 + 16 * g) ^ (n16 << 4)));
      #pragma unroll
      for (int kt = 0; kt < 8; ++kt)
        afB[kt] = *(const bf16x8*)(sB0 + n16 * 512
                                   + ((kt * 64 + 16 * g) ^ (n16 << 4)));

      f32x4 accA[2], accB[2];
      #pragma unroll
      for (int c = 0; c < 2; ++c) {
        accA[c] = (f32x4){0.f, 0.f, 0.f, 0.f};
        accB[c] = (f32x4){0.f, 0.f, 0.f, 0.f};
      }
      #pragma unroll
      for (int kt = 0; kt < 8; ++kt)
        #pragma unroll
        for (int c = 0; c < 2; ++c)
          accA[c] = __builtin_amdgcn_mfma_f32_16x16x32_bf16(
              afA[kt], bfrag[c][kt], accA[c], 0, 0, 0);
      #pragma unroll
      for (int kt = 0; kt < 8; ++kt)
        #pragma unroll
        for (int c = 0; c < 2; ++c)
          accB[c] = __builtin_amdgcn_mfma_f32_16x16x32_bf16(
              afB[kt], bfrag[c][kt], accB[c], 0, 0, 0);

      float zA[2][4], zB[2][4];
      #pragma unroll
      for (int c = 0; c < 2; ++c)
        #pragma unroll
        for (int i = 0; i < 4; ++i) {
          zA[c][i] = accA[c][i] + hAe[c][i];
          zB[c][i] = accB[c][i] + hBe[c][i];
        }

      if (pf) {   // refill even-h for t+2 (fire-and-forget across barrier)
        #pragma unroll
        for (int c = 0; c < 2; ++c)
          #pragma unroll
          for (int i = 0; i < 4; ++i) {
            hAe[c][i] = *(const float*)(outA + goff[c][i] + 2048);
            hBe[c][i] = *(const float*)(outB + goff[c][i] + 2048);
          }
      }

      #pragma unroll
      for (int c = 0; c < 2; ++c) {
        const int u = 32 * w + 16 * c + n16;
        #pragma unroll
        for (int i = 0; i < 4; ++i) {
          float eA = exp2f(zA[c][i] * LOG2E2);
          float rA = __builtin_amdgcn_rcpf(eA + 1.0f);
          float nA = fmaf(-2.0f * EPS_, rA, sfA[c][i] + EPS_);
          sfA[c][i] = nA;
          *(short*)(sA1 + sb_byte(4 * g + i, u)) = f2bf_fast(nA);
          *(float*)(outAw + goff[c][i]) = nA;

          float eB = exp2f(zB[c][i] * LOG2E2);
          float rB = __builtin_amdgcn_rcpf(eB + 1.0f);
          float nB = fmaf(-2.0f * EPS_, rB, sfB[c][i] + EPS_);
          sfB[c][i] = nB;
          *(short*)(sB1 + sb_byte(4 * g + i, u)) = f2bf_fast(nB);
          *(float*)(outBw + goff[c][i]) = nB;
        }
      }

      asm volatile("" ::: "memory");
      asm volatile("s_waitcnt lgkmcnt(0)" ::: "memory");
      __builtin_amdgcn_s_barrier();
      asm volatile("" ::: "memory");
    }

    // ================= odd step: read s?1, write s?0 ======================
    {
      bf16x8 afA[8], afB[8];
      #pragma unroll
      for (int kt = 0; kt < 8; ++kt)
        afA[kt] = *(const bf16x8*)(sA1 + n16 * 512
                                   + ((kt * 64 + 16 * g) ^ (n16 << 4)));
      #pragma unroll
      for (int kt = 0; kt < 8; ++kt)
        afB[kt] = *(const bf16x8*)(sB1 + n16 * 512
                                   + ((kt * 64 + 16 * g) ^ (n16 << 4)));

      f32x4 accA[2], accB[2];
      #pragma unroll
      for (int c = 0; c < 2; ++c) {
        accA[c] = (f32x4){0.f, 0.f, 0.f, 0.f};
        accB[c] = (f32x4){0.f, 0.f, 0.f, 0.f};
      }
      #pragma unroll
      for (int kt = 0; kt < 8; ++kt)
        #pragma unroll
        for (int c = 0; c < 2; ++c)
          accA[c] = __builtin_amdgcn_mfma_f32_16x16x32_bf16(
              afA[kt], bfrag[c][kt], accA[c], 0, 0, 0);
      #pragma unroll
      for (int kt = 0; kt < 8; ++kt)
        #pragma unroll
        for (int c = 0; c < 2; ++c)
          accB[c] = __builtin_amdgcn_mfma_f32_16x16x32_bf16(
              afB[kt], bfrag[c][kt], accB[c], 0, 0, 0);

      float zA[2][4], zB[2][4];
      #pragma unroll
      for (int c = 0; c < 2; ++c)
        #pragma unroll
        for (int i = 0; i < 4; ++i) {
          zA[c][i] = accA[c][i] + hAo[c][i];
          zB[c][i] = accB[c][i] + hBo[c][i];
        }

      if (pf) {   // refill odd-h for t+2
        #pragma unroll
        for (int c = 0; c < 2; ++c)
          #pragma unroll
          for (int i = 0; i < 4; ++i) {
            hAo[c][i] = *(const float*)(outA + goff[c][i] + 3072);
            hBo[c][i] = *(const float*)(outB + goff[c][i] + 3072);
          }
      }

      #pragma unroll
      for (int c = 0; c < 2; ++c) {
        const int u = 32 * w + 16 * c + n16;
        #pragma unroll
        for (int i = 0; i < 4; ++i) {
          float eA = exp2f(zA[c][i] * LOG2E2);
          float rA = __builtin_amdgcn_rcpf(eA + 1.0f);
          float nA = fmaf(-2.0f * EPS_, rA, sfA[c][i] + EPS_);
          sfA[c][i] = nA;
          *(short*)(sA0 + sb_byte(4 * g + i, u)) = f2bf_fast(nA);
          *(float*)(outAw + goff[c][i] + 1024) = nA;

          float eB = exp2f(zB[c][i] * LOG2E2);
          float rB = __builtin_amdgcn_rcpf(eB + 1.0f);
          float nB = fmaf(-2.0f * EPS_, rB, sfB[c][i] + EPS_);
          sfB[c][i] = nB;
          *(short*)(sB0 + sb_byte(4 * g + i, u)) = f2bf_fast(nB);
          *(float*)(outBw + goff[c][i] + 1024) = nB;
        }
      }

      // advance offsets by 2 timesteps (shared by both groups)
      #pragma unroll
      for (int c = 0; c < 2; ++c)
        #pragma unroll
        for (int i = 0; i < 4; ++i) goff[c][i] += 2048u;

      asm volatile("" ::: "memory");
      asm volatile("s_waitcnt lgkmcnt(0)" ::: "memory");
      __builtin_amdgcn_s_barrier();
      asm volatile("" ::: "memory");
    }
  }
}

extern "C" void kernel_launch(void* const* d_in, const int* in_sizes, int n_in,
                              void* d_out, int out_size, void* d_ws, size_t ws_size,
                              hipStream_t stream) {
  const float* x    = (const float*)d_in[0];  // [B,T,D]
  const float* V    = (const float*)d_in[1];  // [D,U]
  const float* W    = (const float*)d_in[2];  // [U,U]
  const float* bias = (const float*)d_in[3];  // [U]
  const float* x0   = (const float*)d_in[4];  // [U]
  float* out = (float*)d_out;                 // [B,T,U]

  // Stage h = x@V + bias into d_out, then scan overwrites it in place.
  h_gemm_kernel<<<(B_ * T_) / HG_ROWS, 256, 0, stream>>>(x, V, bias, out);
  scan_mfma_kernel<<<NBLK, 512, 0, stream>>>(W, x0, out);
}

// Round 14
// 867.550 us; speedup vs baseline: 2.2345x; 2.2345x over previous
//
#include <hip/hip_runtime.h>
#include <hip/hip_bf16.h>
#include <cmath>

#define B_ 128
#define T_ 1024
#define D_ 128
#define U_ 256
#define EPS_ 0.01f
#define GAMMA_ 0.01f
#define NB 16            // batches per scan block
#define NBLK (B_ / NB)   // 8 scan blocks

typedef __attribute__((ext_vector_type(8))) short bf16x8;
typedef __attribute__((ext_vector_type(4))) float f32x4;

// f32 -> bf16 round-to-nearest-even (bit math)
static __device__ __forceinline__ short f2bf(float f) {
  unsigned u = __builtin_bit_cast(unsigned, f);
  unsigned r = (u + 0x7FFFu + ((u >> 16) & 1u)) >> 16;
  return (short)r;
}
// native v_cvt (1 op, RTE)
static __device__ __forceinline__ short f2bf_fast(float f) {
  __hip_bfloat16 b(f);
  return __builtin_bit_cast(short, b);
}

// Scan-state swizzle: s[16 rows][256 units] bf16, row stride 512 B; XOR byte
// bits 4-7 with (row&15) -> reads and writes <=2-way (r9: conflicts = 0).
static __device__ __forceinline__ int sb_byte(int j, int u) {
  return j * 512 + ((u * 2) ^ ((j & 15) << 4));
}

// ============ Kernel 1: h = x @ V + bias via bf16 MFMA ======================
// 2048 blocks x 256 thr (4 waves). Block tile: 64 rows x 256 cols, K=128.
// A: x-tile bf16 in LDS [64][128] (16 KB); B: V bf16 TRANSPOSED in LDS
// [u=256][k=128] (64 KB) so B-fragments read k-contiguous b128. Both
// XOR-swizzled (byte bits 4-7 ^ row&15). Wave w owns cols [64w, 64w+64).
// Slot map (g,e) -> k = kt*32+8g+e on A and B sides (lane-uniform);
// C/D layout (m89-verified): col = l&15, row = 4*(l>>4) + reg.
#define GB_ROWS 64

__global__ __launch_bounds__(256, 2) void h_gemm_mfma(
    const float* __restrict__ x, const float* __restrict__ V,
    const float* __restrict__ bias, float* __restrict__ out)
{
  __shared__ __align__(16) char Alds[GB_ROWS * 256];   // 16 KB bf16 [r][2k^swz]
  __shared__ __align__(16) char Blds[U_ * 256];        // 64 KB bf16 [u][2k^swz]

  const int tid = threadIdx.x;
  const int w = tid >> 6;
  const int l = tid & 63;
  const int g = l >> 4;
  const int n16 = l & 15;
  const size_t row0 = (size_t)blockIdx.x * GB_ROWS;

  // ---- stage A: x[row0..row0+64][0..128] f32 -> bf16, swizzled b64 writes
  {
    const float4* xg = reinterpret_cast<const float4*>(x + row0 * D_);
    #pragma unroll
    for (int ii = 0; ii < 8; ++ii) {
      const int idx4 = ii * 256 + tid;      // coalesced across lanes
      float4 f = xg[idx4];
      const int r = idx4 >> 5;              // 32 float4 per 128-f32 row
      const int k = (idx4 & 31) * 4;
      short4 p;
      p.x = f2bf_fast(f.x); p.y = f2bf_fast(f.y);
      p.z = f2bf_fast(f.z); p.w = f2bf_fast(f.w);
      *(short4*)(&Alds[r * 256 + ((2 * k) ^ ((r & 15) << 4))]) = p;
    }
  }

  // ---- stage B: thread owns column u = tid; 128 coalesced scalar loads,
  // 32 swizzled b64 writes (k-contiguous in the transposed layout)
  {
    const int u = tid;
    const int swz = (u & 15) << 4;
    #pragma unroll 8
    for (int k4 = 0; k4 < 32; ++k4) {
      const int k = k4 * 4;
      float v0 = V[(size_t)(k + 0) * U_ + u];
      float v1 = V[(size_t)(k + 1) * U_ + u];
      float v2 = V[(size_t)(k + 2) * U_ + u];
      float v3 = V[(size_t)(k + 3) * U_ + u];
      short4 p;
      p.x = f2bf_fast(v0); p.y = f2bf_fast(v1);
      p.z = f2bf_fast(v2); p.w = f2bf_fast(v3);
      *(short4*)(&Blds[u * 256 + ((2 * k) ^ swz)]) = p;
    }
  }

  __syncthreads();

  // ---- bias for this wave's 4 n-tiles
  float bnt[4];
  #pragma unroll
  for (int nt = 0; nt < 4; ++nt) bnt[nt] = bias[64 * w + 16 * nt + n16];

  // ---- B fragments: [nt][kt], b128 from transposed V
  bf16x8 bfr[4][4];
  #pragma unroll
  for (int nt = 0; nt < 4; ++nt)
    #pragma unroll
    for (int kt = 0; kt < 4; ++kt)
      bfr[nt][kt] = *(const bf16x8*)(
          &Blds[(64 * w + 16 * nt + n16) * 256
                + ((kt * 64 + 16 * g) ^ (n16 << 4))]);

  // ---- compute: 4 kt x 4 m x 4 nt mfma
  f32x4 acc[4][4];
  #pragma unroll
  for (int m = 0; m < 4; ++m)
    #pragma unroll
    for (int nt = 0; nt < 4; ++nt) acc[m][nt] = (f32x4){0.f, 0.f, 0.f, 0.f};

  #pragma unroll
  for (int kt = 0; kt < 4; ++kt) {
    bf16x8 af[4];
    #pragma unroll
    for (int m = 0; m < 4; ++m)
      af[m] = *(const bf16x8*)(
          &Alds[(16 * m + n16) * 256 + ((kt * 64 + 16 * g) ^ (n16 << 4))]);
    #pragma unroll
    for (int m = 0; m < 4; ++m)
      #pragma unroll
      for (int nt = 0; nt < 4; ++nt)
        acc[m][nt] = __builtin_amdgcn_mfma_f32_16x16x32_bf16(
            af[m], bfr[nt][kt], acc[m][nt], 0, 0, 0);
  }

  // ---- store h = acc + bias (f32), coalesced within 16-lane groups
  float* og = out + row0 * U_;
  #pragma unroll
  for (int m = 0; m < 4; ++m)
    #pragma unroll
    for (int nt = 0; nt < 4; ++nt) {
      const int u = 64 * w + 16 * nt + n16;
      #pragma unroll
      for (int i = 0; i < 4; ++i)
        og[(size_t)(16 * m + 4 * g + i) * U_ + u] = acc[m][nt][i] + bnt[nt];
    }
}

// ============ Kernel 2: MFMA scan (r8 structure, r9 swizzle) ================
// 8 blocks x 512 threads (8 waves, 2/SIMD). Z[16][256] = S_bf16 @ M_bf16.
// Wave w owns u-tiles {2w, 2w+1}. M fragments permanent in VGPRs. S double-
// buffered in LDS (row&15 swizzle, conflicts=0 per r9). __syncthreads per
// step + 1-deep h prefetch with rotation (r8 = best measured, 861 us).
__global__ __launch_bounds__(512, 2) void scan_mfma_kernel(
    const float* __restrict__ W, const float* __restrict__ x0,
    float* __restrict__ out)
{
  __shared__ __align__(16) char sbuf[2][16 * 512];

  const int tid = threadIdx.x;
  const int w = tid >> 6;     // wave 0..7
  const int l = tid & 63;
  const int g = l >> 4;       // 0..3
  const int n16 = l & 15;
  const int b0 = blockIdx.x * NB;

  // ---- B fragments (static M columns), 2 c-tiles per wave
  bf16x8 bfrag[2][8];
  #pragma unroll
  for (int c = 0; c < 2; ++c) {
    const int u = 32 * w + 16 * c + n16;
    #pragma unroll
    for (int kt = 0; kt < 8; ++kt) {
      #pragma unroll
      for (int e = 0; e < 8; ++e) {
        const int k = kt * 32 + 8 * g + e;
        float mv = W[(size_t)k * U_ + u] - W[(size_t)u * U_ + k]
                   - ((k == u) ? GAMMA_ : 0.0f);
        bfrag[c][kt][e] = f2bf(mv);
      }
    }
  }

  // ---- f32 master state: lane owns rows 4g+i, cols u(c)
  float s_f32[2][4];
  #pragma unroll
  for (int c = 0; c < 2; ++c) {
    float v = x0[32 * w + 16 * c + n16];
    #pragma unroll
    for (int i = 0; i < 4; ++i) s_f32[c][i] = v;
  }

  // ---- init bf16 state buffer 0 (threads 0..255 handle unit u=tid)
  if (tid < U_) {
    short v = f2bf(x0[tid]);
    #pragma unroll
    for (int j = 0; j < 16; ++j)
      *(short*)(&sbuf[0][sb_byte(j, tid)]) = v;
  }
  __syncthreads();

  // ---- h preload for t=0
  float h_cur[2][4], h_nxt[2][4];
  #pragma unroll
  for (int c = 0; c < 2; ++c) {
    const int u = 32 * w + 16 * c + n16;
    #pragma unroll
    for (int i = 0; i < 4; ++i)
      h_cur[c][i] = out[(size_t)(b0 + 4 * g + i) * (T_ * U_) + u];
  }

  for (int t = 0; t < T_; ++t) {
    // ---- issue h[t+1] loads first
    {
      const int tn = (t + 1 < T_) ? t + 1 : t;
      #pragma unroll
      for (int c = 0; c < 2; ++c) {
        const int u = 32 * w + 16 * c + n16;
        #pragma unroll
        for (int i = 0; i < 4; ++i)
          h_nxt[c][i] = out[(size_t)(b0 + 4 * g + i) * (T_ * U_)
                            + (size_t)tn * U_ + u];
      }
    }

    // ---- A fragments from sbuf[t&1]: row n16, slot (g,e) -> u = kt*32+8g+e
    const char* sb = sbuf[t & 1];
    bf16x8 af[8];
    #pragma unroll
    for (int kt = 0; kt < 8; ++kt)
      af[kt] = *(const bf16x8*)(sb + n16 * 512
                                + ((kt * 64 + 16 * g) ^ (n16 << 4)));

    // ---- MFMA: 2 independent acc chains x 8 k-tiles
    f32x4 acc[2];
    #pragma unroll
    for (int c = 0; c < 2; ++c) acc[c] = (f32x4){0.f, 0.f, 0.f, 0.f};
    #pragma unroll
    for (int kt = 0; kt < 8; ++kt)
      #pragma unroll
      for (int c = 0; c < 2; ++c)
        acc[c] = __builtin_amdgcn_mfma_f32_16x16x32_bf16(
            af[kt], bfrag[c][kt], acc[c], 0, 0, 0);

    // ---- epilogue: z = d + h; tanh; state update; bf16 S write + f32 out
    char* sw = sbuf[(t & 1) ^ 1];
    #pragma unroll
    for (int c = 0; c < 2; ++c) {
      const int u = 32 * w + 16 * c + n16;
      #pragma unroll
      for (int i = 0; i < 4; ++i) {
        float z = acc[c][i] + h_cur[c][i];
        float e2 = __expf(2.0f * z);
        float th = 1.0f - 2.0f * __builtin_amdgcn_rcpf(e2 + 1.0f);
        float ns = s_f32[c][i] + EPS_ * th;
        s_f32[c][i] = ns;
        *(short*)(sw + sb_byte(4 * g + i, u)) = f2bf_fast(ns);
        out[(size_t)(b0 + 4 * g + i) * (T_ * U_) + (size_t)t * U_ + u] = ns;
      }
    }

    // ---- rotate h prefetch
    #pragma unroll
    for (int c = 0; c < 2; ++c)
      #pragma unroll
      for (int i = 0; i < 4; ++i) h_cur[c][i] = h_nxt[c][i];

    __syncthreads();
  }
}

extern "C" void kernel_launch(void* const* d_in, const int* in_sizes, int n_in,
                              void* d_out, int out_size, void* d_ws, size_t ws_size,
                              hipStream_t stream) {
  const float* x    = (const float*)d_in[0];  // [B,T,D]
  const float* V    = (const float*)d_in[1];  // [D,U]
  const float* W    = (const float*)d_in[2];  // [U,U]
  const float* bias = (const float*)d_in[3];  // [U]
  const float* x0   = (const float*)d_in[4];  // [U]
  float* out = (float*)d_out;                 // [B,T,U]

  // Stage h = x@V + bias into d_out (bf16 MFMA), then scan in place.
  h_gemm_mfma<<<(B_ * T_) / GB_ROWS, 256, 0, stream>>>(x, V, bias, out);
  scan_mfma_kernel<<<NBLK, 512, 0, stream>>>(W, x0, out);
}